// Round 4
// baseline (808.209 us; speedup 1.0000x reference)
//
#include <hip/hip_runtime.h>
#include <hip/hip_bf16.h>
#include <math.h>

#define B_     16
#define L_     4096
#define H_     512
#define NH     32
#define OUT_   256
#define NPRED_ 128
#define CCH    8      // chunks along L
#define LCH    512    // chunk length

typedef __attribute__((ext_vector_type(8))) short bf16x8;
typedef __attribute__((ext_vector_type(4))) float f32x4;

// ---------------- prep: select + bf16-convert weights ----------------
__global__ void prep_kernel(const float* __restrict__ conv_w, const float* __restrict__ conv_b,
                            const float* __restrict__ out_w,
                            __hip_bfloat16* __restrict__ Wsel, float* __restrict__ bselp,
                            __hip_bfloat16* __restrict__ outw)
{
    int idx = blockIdx.x * blockDim.x + threadIdx.x;
    if (idx < 256 * 512) {
        int r = idx >> 9, hcol = idx & 511;
        int src = (r < 128) ? (384 + r) : (768 + r);   // 896 + (r-128)
        Wsel[idx] = __float2bfloat16(conv_w[src * H_ + hcol]);
    } else if (idx < 256 * 512 + 256 * 4096) {
        int i2 = idx - 256 * 512;
        outw[i2] = __float2bfloat16(out_w[i2]);
    } else if (idx < 256 * 512 + 256 * 4096 + 256) {
        int r = idx - 256 * 512 - 256 * 4096;
        int src = (r < 128) ? (384 + r) : (768 + r);
        bselp[r] = conv_b[src];
    }
}

// ---------------- scan pass1: per-chunk end-state, 16 states/lane, 32 h/wave ----------------
// grid (16 b, 16 hgroup32, 2 cq), block 256 = 4 waves; wave w -> chunk cq*4+w.
// lane&31 = h-local, lane>>5 = which 16-state half. No LDS, no barriers.
__global__ __launch_bounds__(256)
void scan_pass1(const float* __restrict__ inp, const float* __restrict__ log_dt,
                const float* __restrict__ log_A_real, const float* __restrict__ A_imag,
                float2* __restrict__ M)
{
    const int b = blockIdx.x, hg = blockIdx.y, cq = blockIdx.z;
    const int tid = threadIdx.x;
    const int wv = tid >> 6, lane = tid & 63;
    const int c = cq * 4 + wv;
    const int hl = lane & 31, nh0 = (lane >> 5) * 16;
    const int h = hg * 32 + hl;

    float wr[16], wi[16], sr[16], si[16];
    const float dt = expf(log_dt[h]);
#pragma unroll
    for (int j = 0; j < 16; ++j) {
        const int n = nh0 + j;
        const float Ar = -expf(log_A_real[h * NH + n]);
        const float Ai = A_imag[h * NH + n];
        const float er = expf(Ar * dt);
        wr[j] = er * cosf(Ai * dt);
        wi[j] = er * sinf(Ai * dt);
        sr[j] = 0.f; si[j] = 0.f;
    }

    const float* xp = inp + ((size_t)b * L_ + (size_t)c * LCH) * H_ + h;
    float xq0 = xp[0 * (size_t)H_];
    float xq1 = xp[1 * (size_t)H_];
    float xq2 = xp[2 * (size_t)H_];
    float xq3 = xp[3 * (size_t)H_];
#pragma unroll 4
    for (int l = 0; l < LCH; ++l) {
        int lp = l + 4; lp = (lp < LCH) ? lp : (LCH - 1);
        const float xf = xp[(size_t)lp * H_];
        const float x = xq0;
#pragma unroll
        for (int j = 0; j < 16; ++j) {
            const float nsr = fmaf(wr[j], sr[j], fmaf(-wi[j], si[j], x));
            const float nsi = fmaf(wr[j], si[j], wi[j] * sr[j]);
            sr[j] = nsr; si[j] = nsi;
        }
        xq0 = xq1; xq1 = xq2; xq2 = xq3; xq3 = xf;
    }

    float2* Mp = M + (((size_t)b * CCH + c) * H_ + h) * NH + nh0;
#pragma unroll
    for (int j = 0; j < 16; j += 2) {
        float4 v; v.x = sr[j]; v.y = si[j]; v.z = sr[j + 1]; v.w = si[j + 1];
        *(float4*)&Mp[j] = v;
    }
}

// ---------------- scan pass2: combine chunk carries IN-PLACE over M ----------------
// one thread per (b,h,n); M[c] becomes the state ENTERING chunk c.
__global__ __launch_bounds__(256)
void scan_pass2(const float* __restrict__ log_dt, const float* __restrict__ log_A_real,
                const float* __restrict__ A_imag, float2* __restrict__ M)
{
    const int idx = blockIdx.x * 256 + threadIdx.x;    // 262144 total
    const int n = idx & 31, h = (idx >> 5) & 511, b = idx >> 14;
    const float dt = expf(log_dt[h]);
    const float Ar = -expf(log_A_real[h * NH + n]);
    const float Ai = A_imag[h * NH + n];
    const float er = expf(Ar * dt);
    float wr = er * cosf(Ai * dt), wi = er * sinf(Ai * dt);
    // w^512 via 9 squarings (avoids large-argument trig)
#pragma unroll
    for (int s = 0; s < 9; ++s) {
        float nr = wr * wr - wi * wi;
        float ni = 2.0f * wr * wi;
        wr = nr; wi = ni;
    }
    float sre = 0.f, sim = 0.f;
#pragma unroll
    for (int c = 0; c < CCH; ++c) {
        const size_t mi_ = (((size_t)b * CCH + c) * H_ + h) * NH + n;
        float2 m = M[mi_];
        M[mi_] = make_float2(sre, sim);
        float nr = fmaf(wr, sre, fmaf(-wi, sim, m.x));
        float ni = fmaf(wr, sim, fmaf(wi, sre, m.y));
        sre = nr; sim = ni;
    }
}

// ---------------- scan pass3: seeded scan + y + D*x + gelu -> gT bf16 ----------------
// same decomposition as pass1; y reduced with ONE shfl_xor(.,32); no LDS.
__global__ __launch_bounds__(256)
void scan_pass3(const float* __restrict__ inp, const float* __restrict__ C,
                const float* __restrict__ log_dt, const float* __restrict__ log_A_real,
                const float* __restrict__ A_imag, const float* __restrict__ Dv,
                const float2* __restrict__ Sin, __hip_bfloat16* __restrict__ gT)
{
    const int b = blockIdx.x, hg = blockIdx.y, cq = blockIdx.z;
    const int tid = threadIdx.x;
    const int wv = tid >> 6, lane = tid & 63;
    const int c = cq * 4 + wv;
    const int hl = lane & 31, nh0 = (lane >> 5) * 16;
    const int h = hg * 32 + hl;

    float wr[16], wi[16], cr[16], cni[16], sr[16], si[16];
    const float dt = expf(log_dt[h]);
    const float2* Sp = Sin + (((size_t)b * CCH + c) * H_ + h) * NH + nh0;
#pragma unroll
    for (int j = 0; j < 16; ++j) {
        const int n = nh0 + j;
        const float Ar = -expf(log_A_real[h * NH + n]);
        const float Ai = A_imag[h * NH + n];
        const float er = expf(Ar * dt);
        const float wrr = er * cosf(Ai * dt);
        const float wii = er * sinf(Ai * dt);
        const float m2 = Ar * Ar + Ai * Ai;
        const float nr = wrr - 1.0f, nim = wii;
        const float qr = (nr * Ar + nim * Ai) / m2;
        const float qi = (nim * Ar - nr * Ai) / m2;
        const float Cr = C[(h * NH + n) * 2 + 0];
        const float Ci = C[(h * NH + n) * 2 + 1];
        wr[j]  = wrr;  wi[j] = wii;
        cr[j]  =  2.0f * (Cr * qr - Ci * qi);
        cni[j] = -2.0f * (Cr * qi + Ci * qr);
        float2 sv = Sp[j];
        sr[j] = sv.x; si[j] = sv.y;
    }
    const float Dh = Dv[h];

    const float* xp = inp + ((size_t)b * L_ + (size_t)c * LCH) * H_ + h;
    __hip_bfloat16* gp = gT + ((size_t)b * L_ + (size_t)c * LCH) * H_ + h;

    float xq0 = xp[0 * (size_t)H_];
    float xq1 = xp[1 * (size_t)H_];
    float xq2 = xp[2 * (size_t)H_];
    float xq3 = xp[3 * (size_t)H_];
#pragma unroll 2
    for (int l = 0; l < LCH; ++l) {
        int lp = l + 4; lp = (lp < LCH) ? lp : (LCH - 1);
        const float xf = xp[(size_t)lp * H_];
        const float x = xq0;
        float y = 0.0f;
#pragma unroll
        for (int j = 0; j < 16; ++j) {
            const float nsr = fmaf(wr[j], sr[j], fmaf(-wi[j], si[j], x));
            const float nsi = fmaf(wr[j], si[j], wi[j] * sr[j]);
            sr[j] = nsr; si[j] = nsi;
            y = fmaf(cr[j], nsr, y);
            y = fmaf(cni[j], nsi, y);
        }
        y += __shfl_xor(y, 32);                    // combine the two state-halves
        const float v = fmaf(Dh, x, y);
        const float ge = 0.5f * v * (1.0f + erff(v * 0.70710678f));
        if (lane < 32) gp[(size_t)l * H_] = __float2bfloat16(ge);
        xq0 = xq1; xq1 = xq2; xq2 = xq3; xq3 = xf;
    }
}

__device__ __forceinline__ unsigned short bf16bits(float f) {
    __hip_bfloat16 hv = __float2bfloat16(f);
    return *reinterpret_cast<unsigned short*>(&hv);
}

// ---------------- GEMM1 + gate ----------------
__global__ __launch_bounds__(512)
void gemm1_kernel(const __hip_bfloat16* __restrict__ gT, const __hip_bfloat16* __restrict__ Wsel,
                  const float* __restrict__ bsel, __hip_bfloat16* __restrict__ gated)
{
    const int b  = blockIdx.y;
    const int l0 = blockIdx.x * 128;
    const int tid = threadIdx.x;
    const int wid = tid >> 6, lane = tid & 63;
    const int wrr = wid >> 2;      // 0..1
    const int wcc = wid & 3;       // 0..3
    const int lr  = lane & 15;
    const int lk8 = (lane >> 4) * 8;

    __shared__ short As[128][40];
    __shared__ short Bs[256][40];

    f32x4 acc[4][4];
#pragma unroll
    for (int i = 0; i < 4; ++i)
#pragma unroll
        for (int j = 0; j < 4; ++j) acc[i][j] = (f32x4){0.f, 0.f, 0.f, 0.f};

    const short* gsrc = (const short*)gT + ((size_t)b * L_ + l0) * H_;
    const short* wsrc = (const short*)Wsel;
    const int arow = tid >> 2, aseg = tid & 3;

    for (int ks = 0; ks < 16; ++ks) {
        const int k0 = ks * 32;
        uint4 av  = *(const uint4*)(gsrc + (size_t)arow * H_ + k0 + aseg * 8);
        uint4 bv0 = *(const uint4*)(wsrc + (size_t)arow * 512 + k0 + aseg * 8);
        uint4 bv1 = *(const uint4*)(wsrc + (size_t)(arow + 128) * 512 + k0 + aseg * 8);
        *(uint4*)&As[arow][aseg * 8]       = av;
        *(uint4*)&Bs[arow][aseg * 8]       = bv0;
        *(uint4*)&Bs[arow + 128][aseg * 8] = bv1;
        __syncthreads();

        bf16x8 af[4], bfr[4];
#pragma unroll
        for (int mi = 0; mi < 4; ++mi)
            af[mi] = *(const bf16x8*)&As[wrr * 64 + mi * 16 + lr][lk8];
#pragma unroll
        for (int ni = 0; ni < 4; ++ni) {
            int col = (ni < 2) ? (wcc * 32 + ni * 16) : (128 + wcc * 32 + (ni - 2) * 16);
            bfr[ni] = *(const bf16x8*)&Bs[col + lr][lk8];
        }
#pragma unroll
        for (int mi = 0; mi < 4; ++mi)
#pragma unroll
            for (int ni = 0; ni < 4; ++ni)
                acc[mi][ni] = __builtin_amdgcn_mfma_f32_16x16x32_bf16(af[mi], bfr[ni], acc[mi][ni], 0, 0, 0);
        __syncthreads();
    }

    const int lj4 = (lane >> 4) * 4;
#pragma unroll
    for (int mi = 0; mi < 4; ++mi) {
#pragma unroll
        for (int ni = 0; ni < 2; ++ni) {
            const int oa = wcc * 32 + ni * 16 + lr;
            const float ba  = bsel[oa];
            const float bbv = bsel[oa + 128];
            ushort4 pack;
            unsigned short* pu = (unsigned short*)&pack;
#pragma unroll
            for (int j = 0; j < 4; ++j) {
                float za = acc[mi][ni][j] + ba;
                float zb = acc[mi][ni + 2][j] + bbv;
                float gv = za * (1.0f / (1.0f + expf(-zb)));
                pu[j] = bf16bits(gv);
            }
            const int lrow = l0 + wrr * 64 + mi * 16 + lj4;
            *(ushort4*)((unsigned short*)gated + ((size_t)b * NPRED_ + oa) * L_ + lrow) = pack;
        }
    }
}

// ---------------- GEMM2: 64x64 tiles, BK=64, grid 128 blocks ----------------
__global__ __launch_bounds__(256)
void gemm2_kernel(const __hip_bfloat16* __restrict__ gated, const __hip_bfloat16* __restrict__ outw,
                  const float* __restrict__ outb, float* __restrict__ outp)
{
    const int b  = blockIdx.y;
    const int ot = blockIdx.x & 3, ht = blockIdx.x >> 2;
    const int o0 = ot * 64, hh0 = ht * 64;
    const int tid = threadIdx.x;
    const int wid = tid >> 6, lane = tid & 63;
    const int wrr = wid >> 1;      // 0..1
    const int wcc = wid & 1;       // 0..1
    const int lr  = lane & 15;
    const int lk8 = (lane >> 4) * 8;

    __shared__ short As[64][72];   // [hh][k] BK=64, +8 pad
    __shared__ short Bs[64][72];   // [o][k]

    f32x4 acc[2][2];
#pragma unroll
    for (int i = 0; i < 2; ++i)
#pragma unroll
        for (int j = 0; j < 2; ++j) acc[i][j] = (f32x4){0.f, 0.f, 0.f, 0.f};

    const short* asrc = (const short*)gated + ((size_t)b * NPRED_ + hh0) * L_;
    const short* bsrc = (const short*)outw + (size_t)o0 * L_;
    const int row = tid >> 2, seg = tid & 3;

    for (int ks = 0; ks < 64; ++ks) {
        const int k0 = ks * 64;
        uint4 a0 = *(const uint4*)(asrc + (size_t)row * L_ + k0 + seg * 8);
        uint4 a1 = *(const uint4*)(asrc + (size_t)row * L_ + k0 + 32 + seg * 8);
        uint4 b0 = *(const uint4*)(bsrc + (size_t)row * L_ + k0 + seg * 8);
        uint4 b1 = *(const uint4*)(bsrc + (size_t)row * L_ + k0 + 32 + seg * 8);
        __syncthreads();
        *(uint4*)&As[row][seg * 8]      = a0;
        *(uint4*)&As[row][32 + seg * 8] = a1;
        *(uint4*)&Bs[row][seg * 8]      = b0;
        *(uint4*)&Bs[row][32 + seg * 8] = b1;
        __syncthreads();

#pragma unroll
        for (int kk = 0; kk < 2; ++kk) {
            bf16x8 af[2], bfv[2];
#pragma unroll
            for (int mi = 0; mi < 2; ++mi)
                af[mi] = *(const bf16x8*)&As[wrr * 32 + mi * 16 + lr][kk * 32 + lk8];
#pragma unroll
            for (int ni = 0; ni < 2; ++ni)
                bfv[ni] = *(const bf16x8*)&Bs[wcc * 32 + ni * 16 + lr][kk * 32 + lk8];
#pragma unroll
            for (int mi = 0; mi < 2; ++mi)
#pragma unroll
                for (int ni = 0; ni < 2; ++ni)
                    acc[mi][ni] = __builtin_amdgcn_mfma_f32_16x16x32_bf16(af[mi], bfv[ni], acc[mi][ni], 0, 0, 0);
        }
    }

    const int lj4 = (lane >> 4) * 4;
#pragma unroll
    for (int mi = 0; mi < 2; ++mi) {
#pragma unroll
        for (int ni = 0; ni < 2; ++ni) {
            const int og = o0 + wcc * 32 + ni * 16 + lr;
            const float bo = outb[og];
            float4 v;
            v.x = acc[mi][ni][0] + bo;
            v.y = acc[mi][ni][1] + bo;
            v.z = acc[mi][ni][2] + bo;
            v.w = acc[mi][ni][3] + bo;
            const int hh = hh0 + wrr * 32 + mi * 16 + lj4;
            *(float4*)(outp + ((size_t)b * OUT_ + og) * NPRED_ + hh) = v;
        }
    }
}

// ---------------- launch ----------------
extern "C" void kernel_launch(void* const* d_in, const int* in_sizes, int n_in,
                              void* d_out, int out_size, void* d_ws, size_t ws_size,
                              hipStream_t stream)
{
    const float* inp        = (const float*)d_in[0];
    const float* C          = (const float*)d_in[2];
    const float* log_dt     = (const float*)d_in[3];
    const float* log_A_real = (const float*)d_in[4];
    const float* A_imag     = (const float*)d_in[5];
    const float* Dv         = (const float*)d_in[6];
    const float* conv_w     = (const float*)d_in[7];
    const float* conv_b     = (const float*)d_in[8];
    const float* out_w      = (const float*)d_in[9];
    const float* out_b      = (const float*)d_in[10];
    float* outp = (float*)d_out;

    // workspace layout (bytes). M (16 MiB exactly) aliases gated: M is dead
    // before gemm1 writes gated, and M is DISJOINT from gT (pass3 reads M
    // while writing gT). need == 86246400 (proven available round 1/3).
    const size_t off_Wsel  = 0;                         // 262144
    const size_t off_outw  = 262144;                    // 2097152
    const size_t off_bsel  = 2359296;                   // 1024
    const size_t off_gT    = 2360320;                   // 67108864
    const size_t off_gated = 69469184;                  // 16777216
    const size_t off_M     = off_gated;                 // 16*8*512*32*8 = 16777216
    const size_t need      = 86246400;
    if (ws_size < need) return;

    char* ws = (char*)d_ws;
    __hip_bfloat16* Wsel  = (__hip_bfloat16*)(ws + off_Wsel);
    __hip_bfloat16* outw  = (__hip_bfloat16*)(ws + off_outw);
    float*          bselp = (float*)(ws + off_bsel);
    __hip_bfloat16* gT    = (__hip_bfloat16*)(ws + off_gT);
    __hip_bfloat16* gated = (__hip_bfloat16*)(ws + off_gated);
    float2*         M     = (float2*)(ws + off_M);

    const int prep_total = 256 * 512 + 256 * 4096 + 256;
    prep_kernel<<<(prep_total + 255) / 256, 256, 0, stream>>>(conv_w, conv_b, out_w, Wsel, bselp, outw);
    scan_pass1<<<dim3(16, 16, 2), 256, 0, stream>>>(inp, log_dt, log_A_real, A_imag, M);
    scan_pass2<<<1024, 256, 0, stream>>>(log_dt, log_A_real, A_imag, M);
    scan_pass3<<<dim3(16, 16, 2), 256, 0, stream>>>(inp, C, log_dt, log_A_real, A_imag, Dv, M, gT);
    gemm1_kernel<<<dim3(32, 16), 512, 0, stream>>>(gT, Wsel, bselp, gated);
    gemm2_kernel<<<dim3(8, 16), 256, 0, stream>>>(gated, outw, out_b, outp);
}

// Round 5
// 785.918 us; speedup vs baseline: 1.0284x; 1.0284x over previous
//
#include <hip/hip_runtime.h>
#include <hip/hip_bf16.h>
#include <math.h>

#define B_     16
#define L_     4096
#define H_     512
#define NH     32
#define OUT_   256
#define NPRED_ 128
#define CCH    8      // chunks along L
#define LCH    512    // chunk length

typedef __attribute__((ext_vector_type(8))) short bf16x8;
typedef __attribute__((ext_vector_type(4))) float f32x4;

// ---------------- prep: select + bf16-convert weights ----------------
__global__ void prep_kernel(const float* __restrict__ conv_w, const float* __restrict__ conv_b,
                            const float* __restrict__ out_w,
                            __hip_bfloat16* __restrict__ Wsel, float* __restrict__ bselp,
                            __hip_bfloat16* __restrict__ outw)
{
    int idx = blockIdx.x * blockDim.x + threadIdx.x;
    if (idx < 256 * 512) {
        int r = idx >> 9, hcol = idx & 511;
        int src = (r < 128) ? (384 + r) : (768 + r);   // 896 + (r-128)
        Wsel[idx] = __float2bfloat16(conv_w[src * H_ + hcol]);
    } else if (idx < 256 * 512 + 256 * 4096) {
        int i2 = idx - 256 * 512;
        outw[i2] = __float2bfloat16(out_w[i2]);
    } else if (idx < 256 * 512 + 256 * 4096 + 256) {
        int r = idx - 256 * 512 - 256 * 4096;
        int src = (r < 128) ? (384 + r) : (768 + r);
        bselp[r] = conv_b[src];
    }
}

// ---------------- scan pass1: per-chunk end-state ----------------
// 4 lanes/h x 16 h/wave, 8 states/lane. grid (16 b, 32 hg, 2 cq), 4 waves/block,
// wave wv -> chunk cq*4+wv. 4096 waves total = 4/SIMD. No LDS, no barriers.
__global__ __launch_bounds__(256)
void scan_pass1(const float* __restrict__ inp, const float* __restrict__ log_dt,
                const float* __restrict__ log_A_real, const float* __restrict__ A_imag,
                float2* __restrict__ M)
{
    const int b = blockIdx.x, hg = blockIdx.y, cq = blockIdx.z;
    const int tid = threadIdx.x;
    const int wv = tid >> 6, lane = tid & 63;
    const int c = cq * 4 + wv;
    const int hl = lane & 15, nb = (lane >> 4) * 8;   // part*8
    const int h = hg * 16 + hl;

    float wr[8], wi[8], sr[8], si[8];
    const float dt = expf(log_dt[h]);
#pragma unroll
    for (int j = 0; j < 8; ++j) {
        const int n = nb + j;
        const float Ar = -expf(log_A_real[h * NH + n]);
        const float Ai = A_imag[h * NH + n];
        const float er = expf(Ar * dt);
        wr[j] = er * cosf(Ai * dt);
        wi[j] = er * sinf(Ai * dt);
        sr[j] = 0.f; si[j] = 0.f;
    }

    const float* xp = inp + ((size_t)b * L_ + (size_t)c * LCH) * H_ + h;
    float xq0 = xp[0 * (size_t)H_];
    float xq1 = xp[1 * (size_t)H_];
    float xq2 = xp[2 * (size_t)H_];
    float xq3 = xp[3 * (size_t)H_];
#pragma unroll 4
    for (int l = 0; l < LCH; ++l) {
        int lp = l + 4; lp = (lp < LCH) ? lp : (LCH - 1);
        const float xf = xp[(size_t)lp * H_];
        const float x = xq0;
#pragma unroll
        for (int j = 0; j < 8; ++j) {
            const float nsr = fmaf(wr[j], sr[j], fmaf(-wi[j], si[j], x));
            const float nsi = fmaf(wr[j], si[j], wi[j] * sr[j]);
            sr[j] = nsr; si[j] = nsi;
        }
        xq0 = xq1; xq1 = xq2; xq2 = xq3; xq3 = xf;
    }

    float2* Mp = M + (((size_t)b * CCH + c) * H_ + h) * NH + nb;
#pragma unroll
    for (int j = 0; j < 8; j += 2) {
        float4 v; v.x = sr[j]; v.y = si[j]; v.z = sr[j + 1]; v.w = si[j + 1];
        *(float4*)&Mp[j] = v;
    }
}

// ---------------- scan pass2: combine chunk carries IN-PLACE over M ----------------
__global__ __launch_bounds__(256)
void scan_pass2(const float* __restrict__ log_dt, const float* __restrict__ log_A_real,
                const float* __restrict__ A_imag, float2* __restrict__ M)
{
    const int idx = blockIdx.x * 256 + threadIdx.x;    // 262144 total
    const int n = idx & 31, h = (idx >> 5) & 511, b = idx >> 14;
    const float dt = expf(log_dt[h]);
    const float Ar = -expf(log_A_real[h * NH + n]);
    const float Ai = A_imag[h * NH + n];
    const float er = expf(Ar * dt);
    float wr = er * cosf(Ai * dt), wi = er * sinf(Ai * dt);
    // w^512 via 9 squarings (avoids large-argument trig)
#pragma unroll
    for (int s = 0; s < 9; ++s) {
        float nr = wr * wr - wi * wi;
        float ni = 2.0f * wr * wi;
        wr = nr; wi = ni;
    }
    float sre = 0.f, sim = 0.f;
#pragma unroll
    for (int c = 0; c < CCH; ++c) {
        const size_t mi_ = (((size_t)b * CCH + c) * H_ + h) * NH + n;
        float2 m = M[mi_];
        M[mi_] = make_float2(sre, sim);
        float nr = fmaf(wr, sre, fmaf(-wi, sim, m.x));
        float ni = fmaf(wr, sim, fmaf(wi, sre, m.y));
        sre = nr; sim = ni;
    }
}

// ---------------- scan pass3: seeded scan + y + D*x + gelu -> gT bf16 ----------------
// Same decomposition as pass1; y reduced with shfl_xor(16)+shfl_xor(32); no LDS.
__global__ __launch_bounds__(256)
void scan_pass3(const float* __restrict__ inp, const float* __restrict__ C,
                const float* __restrict__ log_dt, const float* __restrict__ log_A_real,
                const float* __restrict__ A_imag, const float* __restrict__ Dv,
                const float2* __restrict__ Sin, __hip_bfloat16* __restrict__ gT)
{
    const int b = blockIdx.x, hg = blockIdx.y, cq = blockIdx.z;
    const int tid = threadIdx.x;
    const int wv = tid >> 6, lane = tid & 63;
    const int c = cq * 4 + wv;
    const int hl = lane & 15, nb = (lane >> 4) * 8;
    const int h = hg * 16 + hl;

    float wr[8], wi[8], cr[8], cni[8], sr[8], si[8];
    const float dt = expf(log_dt[h]);
    const float2* Sp = Sin + (((size_t)b * CCH + c) * H_ + h) * NH + nb;
#pragma unroll
    for (int j = 0; j < 8; ++j) {
        const int n = nb + j;
        const float Ar = -expf(log_A_real[h * NH + n]);
        const float Ai = A_imag[h * NH + n];
        const float er = expf(Ar * dt);
        const float wrr = er * cosf(Ai * dt);
        const float wii = er * sinf(Ai * dt);
        const float m2 = Ar * Ar + Ai * Ai;
        const float nr = wrr - 1.0f, nim = wii;
        const float qr = (nr * Ar + nim * Ai) / m2;
        const float qi = (nim * Ar - nr * Ai) / m2;
        const float Cr = C[(h * NH + n) * 2 + 0];
        const float Ci = C[(h * NH + n) * 2 + 1];
        wr[j]  = wrr;  wi[j] = wii;
        cr[j]  =  2.0f * (Cr * qr - Ci * qi);
        cni[j] = -2.0f * (Cr * qi + Ci * qr);
        float2 sv = Sp[j];
        sr[j] = sv.x; si[j] = sv.y;
    }
    const float Dh = Dv[h];

    const float* xp = inp + ((size_t)b * L_ + (size_t)c * LCH) * H_ + h;
    __hip_bfloat16* gp = gT + ((size_t)b * L_ + (size_t)c * LCH) * H_ + h;

    float xq0 = xp[0 * (size_t)H_];
    float xq1 = xp[1 * (size_t)H_];
    float xq2 = xp[2 * (size_t)H_];
    float xq3 = xp[3 * (size_t)H_];
#pragma unroll 2
    for (int l = 0; l < LCH; ++l) {
        int lp = l + 4; lp = (lp < LCH) ? lp : (LCH - 1);
        const float xf = xp[(size_t)lp * H_];
        const float x = xq0;
        float y = 0.0f;
#pragma unroll
        for (int j = 0; j < 8; ++j) {
            const float nsr = fmaf(wr[j], sr[j], fmaf(-wi[j], si[j], x));
            const float nsi = fmaf(wr[j], si[j], wi[j] * sr[j]);
            sr[j] = nsr; si[j] = nsi;
            y = fmaf(cr[j], nsr, y);
            y = fmaf(cni[j], nsi, y);
        }
        y += __shfl_xor(y, 16);
        y += __shfl_xor(y, 32);
        const float v = fmaf(Dh, x, y);
        // tanh-form gelu: max dev from exact ~3e-4, far below bf16 rounding of gT.
        float u = v * fmaf(0.0356774081f, v * v, 0.797884561f);
        u = fmaxf(u, -15.0f);                      // avoid exp overflow -> NaN in deep tail
        const float e = __expf(-2.0f * u);
        const float th = 1.0f - 2.0f * e * __builtin_amdgcn_rcpf(1.0f + e);
        const float ge = 0.5f * v * (1.0f + th);
        if (lane < 16) gp[(size_t)l * H_] = __float2bfloat16(ge);
        xq0 = xq1; xq1 = xq2; xq2 = xq3; xq3 = xf;
    }
}

__device__ __forceinline__ unsigned short bf16bits(float f) {
    __hip_bfloat16 hv = __float2bfloat16(f);
    return *reinterpret_cast<unsigned short*>(&hv);
}

// ---------------- GEMM1 + gate ----------------
__global__ __launch_bounds__(512)
void gemm1_kernel(const __hip_bfloat16* __restrict__ gT, const __hip_bfloat16* __restrict__ Wsel,
                  const float* __restrict__ bsel, __hip_bfloat16* __restrict__ gated)
{
    const int b  = blockIdx.y;
    const int l0 = blockIdx.x * 128;
    const int tid = threadIdx.x;
    const int wid = tid >> 6, lane = tid & 63;
    const int wrr = wid >> 2;      // 0..1
    const int wcc = wid & 3;       // 0..3
    const int lr  = lane & 15;
    const int lk8 = (lane >> 4) * 8;

    __shared__ short As[128][40];
    __shared__ short Bs[256][40];

    f32x4 acc[4][4];
#pragma unroll
    for (int i = 0; i < 4; ++i)
#pragma unroll
        for (int j = 0; j < 4; ++j) acc[i][j] = (f32x4){0.f, 0.f, 0.f, 0.f};

    const short* gsrc = (const short*)gT + ((size_t)b * L_ + l0) * H_;
    const short* wsrc = (const short*)Wsel;
    const int arow = tid >> 2, aseg = tid & 3;

    for (int ks = 0; ks < 16; ++ks) {
        const int k0 = ks * 32;
        uint4 av  = *(const uint4*)(gsrc + (size_t)arow * H_ + k0 + aseg * 8);
        uint4 bv0 = *(const uint4*)(wsrc + (size_t)arow * 512 + k0 + aseg * 8);
        uint4 bv1 = *(const uint4*)(wsrc + (size_t)(arow + 128) * 512 + k0 + aseg * 8);
        *(uint4*)&As[arow][aseg * 8]       = av;
        *(uint4*)&Bs[arow][aseg * 8]       = bv0;
        *(uint4*)&Bs[arow + 128][aseg * 8] = bv1;
        __syncthreads();

        bf16x8 af[4], bfr[4];
#pragma unroll
        for (int mi = 0; mi < 4; ++mi)
            af[mi] = *(const bf16x8*)&As[wrr * 64 + mi * 16 + lr][lk8];
#pragma unroll
        for (int ni = 0; ni < 4; ++ni) {
            int col = (ni < 2) ? (wcc * 32 + ni * 16) : (128 + wcc * 32 + (ni - 2) * 16);
            bfr[ni] = *(const bf16x8*)&Bs[col + lr][lk8];
        }
#pragma unroll
        for (int mi = 0; mi < 4; ++mi)
#pragma unroll
            for (int ni = 0; ni < 4; ++ni)
                acc[mi][ni] = __builtin_amdgcn_mfma_f32_16x16x32_bf16(af[mi], bfr[ni], acc[mi][ni], 0, 0, 0);
        __syncthreads();
    }

    const int lj4 = (lane >> 4) * 4;
#pragma unroll
    for (int mi = 0; mi < 4; ++mi) {
#pragma unroll
        for (int ni = 0; ni < 2; ++ni) {
            const int oa = wcc * 32 + ni * 16 + lr;
            const float ba  = bsel[oa];
            const float bbv = bsel[oa + 128];
            ushort4 pack;
            unsigned short* pu = (unsigned short*)&pack;
#pragma unroll
            for (int j = 0; j < 4; ++j) {
                float za = acc[mi][ni][j] + ba;
                float zb = acc[mi][ni + 2][j] + bbv;
                float gv = za * (1.0f / (1.0f + expf(-zb)));
                pu[j] = bf16bits(gv);
            }
            const int lrow = l0 + wrr * 64 + mi * 16 + lj4;
            *(ushort4*)((unsigned short*)gated + ((size_t)b * NPRED_ + oa) * L_ + lrow) = pack;
        }
    }
}

// ---------------- GEMM2: 64x64 tiles, BK=64, grid 128 blocks ----------------
__global__ __launch_bounds__(256)
void gemm2_kernel(const __hip_bfloat16* __restrict__ gated, const __hip_bfloat16* __restrict__ outw,
                  const float* __restrict__ outb, float* __restrict__ outp)
{
    const int b  = blockIdx.y;
    const int ot = blockIdx.x & 3, ht = blockIdx.x >> 2;
    const int o0 = ot * 64, hh0 = ht * 64;
    const int tid = threadIdx.x;
    const int wid = tid >> 6, lane = tid & 63;
    const int wrr = wid >> 1;      // 0..1
    const int wcc = wid & 1;       // 0..1
    const int lr  = lane & 15;
    const int lk8 = (lane >> 4) * 8;

    __shared__ short As[64][72];   // [hh][k] BK=64, +8 pad
    __shared__ short Bs[64][72];   // [o][k]

    f32x4 acc[2][2];
#pragma unroll
    for (int i = 0; i < 2; ++i)
#pragma unroll
        for (int j = 0; j < 2; ++j) acc[i][j] = (f32x4){0.f, 0.f, 0.f, 0.f};

    const short* asrc = (const short*)gated + ((size_t)b * NPRED_ + hh0) * L_;
    const short* bsrc = (const short*)outw + (size_t)o0 * L_;
    const int row = tid >> 2, seg = tid & 3;

    for (int ks = 0; ks < 64; ++ks) {
        const int k0 = ks * 64;
        uint4 a0 = *(const uint4*)(asrc + (size_t)row * L_ + k0 + seg * 8);
        uint4 a1 = *(const uint4*)(asrc + (size_t)row * L_ + k0 + 32 + seg * 8);
        uint4 b0 = *(const uint4*)(bsrc + (size_t)row * L_ + k0 + seg * 8);
        uint4 b1 = *(const uint4*)(bsrc + (size_t)row * L_ + k0 + 32 + seg * 8);
        __syncthreads();
        *(uint4*)&As[row][seg * 8]      = a0;
        *(uint4*)&As[row][32 + seg * 8] = a1;
        *(uint4*)&Bs[row][seg * 8]      = b0;
        *(uint4*)&Bs[row][32 + seg * 8] = b1;
        __syncthreads();

#pragma unroll
        for (int kk = 0; kk < 2; ++kk) {
            bf16x8 af[2], bfv[2];
#pragma unroll
            for (int mi = 0; mi < 2; ++mi)
                af[mi] = *(const bf16x8*)&As[wrr * 32 + mi * 16 + lr][kk * 32 + lk8];
#pragma unroll
            for (int ni = 0; ni < 2; ++ni)
                bfv[ni] = *(const bf16x8*)&Bs[wcc * 32 + ni * 16 + lr][kk * 32 + lk8];
#pragma unroll
            for (int mi = 0; mi < 2; ++mi)
#pragma unroll
                for (int ni = 0; ni < 2; ++ni)
                    acc[mi][ni] = __builtin_amdgcn_mfma_f32_16x16x32_bf16(af[mi], bfv[ni], acc[mi][ni], 0, 0, 0);
        }
    }

    const int lj4 = (lane >> 4) * 4;
#pragma unroll
    for (int mi = 0; mi < 2; ++mi) {
#pragma unroll
        for (int ni = 0; ni < 2; ++ni) {
            const int og = o0 + wcc * 32 + ni * 16 + lr;
            const float bo = outb[og];
            float4 v;
            v.x = acc[mi][ni][0] + bo;
            v.y = acc[mi][ni][1] + bo;
            v.z = acc[mi][ni][2] + bo;
            v.w = acc[mi][ni][3] + bo;
            const int hh = hh0 + wrr * 32 + mi * 16 + lj4;
            *(float4*)(outp + ((size_t)b * OUT_ + og) * NPRED_ + hh) = v;
        }
    }
}

// ---------------- launch ----------------
extern "C" void kernel_launch(void* const* d_in, const int* in_sizes, int n_in,
                              void* d_out, int out_size, void* d_ws, size_t ws_size,
                              hipStream_t stream)
{
    const float* inp        = (const float*)d_in[0];
    const float* C          = (const float*)d_in[2];
    const float* log_dt     = (const float*)d_in[3];
    const float* log_A_real = (const float*)d_in[4];
    const float* A_imag     = (const float*)d_in[5];
    const float* Dv         = (const float*)d_in[6];
    const float* conv_w     = (const float*)d_in[7];
    const float* conv_b     = (const float*)d_in[8];
    const float* out_w      = (const float*)d_in[9];
    const float* out_b      = (const float*)d_in[10];
    float* outp = (float*)d_out;

    // workspace layout (bytes). M (16 MiB exactly) aliases gated: M is dead
    // before gemm1 writes gated, and M is DISJOINT from gT (pass3 reads M
    // while writing gT). need == 86246400 (proven available).
    const size_t off_Wsel  = 0;                         // 262144
    const size_t off_outw  = 262144;                    // 2097152
    const size_t off_bsel  = 2359296;                   // 1024
    const size_t off_gT    = 2360320;                   // 67108864
    const size_t off_gated = 69469184;                  // 16777216
    const size_t off_M     = off_gated;                 // 16*8*512*32*8 = 16777216
    const size_t need      = 86246400;
    if (ws_size < need) return;

    char* ws = (char*)d_ws;
    __hip_bfloat16* Wsel  = (__hip_bfloat16*)(ws + off_Wsel);
    __hip_bfloat16* outw  = (__hip_bfloat16*)(ws + off_outw);
    float*          bselp = (float*)(ws + off_bsel);
    __hip_bfloat16* gT    = (__hip_bfloat16*)(ws + off_gT);
    __hip_bfloat16* gated = (__hip_bfloat16*)(ws + off_gated);
    float2*         M     = (float2*)(ws + off_M);

    const int prep_total = 256 * 512 + 256 * 4096 + 256;
    prep_kernel<<<(prep_total + 255) / 256, 256, 0, stream>>>(conv_w, conv_b, out_w, Wsel, bselp, outw);
    scan_pass1<<<dim3(16, 32, 2), 256, 0, stream>>>(inp, log_dt, log_A_real, A_imag, M);
    scan_pass2<<<1024, 256, 0, stream>>>(log_dt, log_A_real, A_imag, M);
    scan_pass3<<<dim3(16, 32, 2), 256, 0, stream>>>(inp, C, log_dt, log_A_real, A_imag, Dv, M, gT);
    gemm1_kernel<<<dim3(32, 16), 512, 0, stream>>>(gT, Wsel, bselp, gated);
    gemm2_kernel<<<dim3(8, 16), 256, 0, stream>>>(gated, outw, out_b, outp);
}

// Round 8
// 580.265 us; speedup vs baseline: 1.3928x; 1.3544x over previous
//
#include <hip/hip_runtime.h>
#include <hip/hip_bf16.h>
#include <math.h>

#define B_     16
#define L_     4096
#define H_     512
#define NH     32
#define OUT_   256
#define NPRED_ 128
#define CCH    8      // chunks along L
#define LCH    512    // chunk length

typedef __attribute__((ext_vector_type(8))) short bf16x8;
typedef __attribute__((ext_vector_type(4))) float f32x4;
typedef __attribute__((ext_vector_type(2))) float f32x2;

// ---------------- prep: select + bf16-convert weights ----------------
__global__ void prep_kernel(const float* __restrict__ conv_w, const float* __restrict__ conv_b,
                            const float* __restrict__ out_w,
                            __hip_bfloat16* __restrict__ Wsel, float* __restrict__ bselp,
                            __hip_bfloat16* __restrict__ outw)
{
    int idx = blockIdx.x * blockDim.x + threadIdx.x;
    if (idx < 256 * 512) {
        int r = idx >> 9, hcol = idx & 511;
        int src = (r < 128) ? (384 + r) : (768 + r);   // 896 + (r-128)
        Wsel[idx] = __float2bfloat16(conv_w[src * H_ + hcol]);
    } else if (idx < 256 * 512 + 256 * 4096) {
        int i2 = idx - 256 * 512;
        outw[i2] = __float2bfloat16(out_w[i2]);
    } else if (idx < 256 * 512 + 256 * 4096 + 256) {
        int r = idx - 256 * 512 - 256 * 4096;
        int src = (r < 128) ? (384 + r) : (768 + r);
        bselp[r] = conv_b[src];
    }
}

// ---------------- scan pass1: per-chunk end-state ----------------
// 4 lanes/h x 16 h/wave, 8 states/lane (4 SoA pairs). grid (16 b, 32 hg, 2 cq),
// 4 waves/block, wave wv -> chunk cq*4+wv. 4096 waves = 4/SIMD. No LDS/barriers.
// SoA packing: SR=(sr0,sr1), SI=(si0,si1) per pair -> update is 4 v_pk ops/pair.
__global__ __launch_bounds__(256)
void scan_pass1(const float* __restrict__ inp, const float* __restrict__ log_dt,
                const float* __restrict__ log_A_real, const float* __restrict__ A_imag,
                float2* __restrict__ M)
{
    const int b = blockIdx.x, hg = blockIdx.y, cq = blockIdx.z;
    const int tid = threadIdx.x;
    const int wv = tid >> 6, lane = tid & 63;
    const int c = cq * 4 + wv;
    const int hl = lane & 15, nb = (lane >> 4) * 8;   // part*8
    const int h = hg * 16 + hl;

    f32x2 WR[4], WI[4], WIN[4], SR[4], SI[4];
    const float dt = expf(log_dt[h]);
#pragma unroll
    for (int g = 0; g < 4; ++g) {
#pragma unroll
        for (int e = 0; e < 2; ++e) {
            const int n = nb + g * 2 + e;
            const float Ar = -expf(log_A_real[h * NH + n]);
            const float Ai = A_imag[h * NH + n];
            const float er = expf(Ar * dt);
            WR[g][e] = er * cosf(Ai * dt);
            WI[g][e] = er * sinf(Ai * dt);
            WIN[g][e] = -WI[g][e];
        }
        SR[g] = (f32x2){0.f, 0.f};
        SI[g] = (f32x2){0.f, 0.f};
    }

    const float* xp = inp + ((size_t)b * L_ + (size_t)c * LCH) * H_ + h;
    float xq0 = xp[0 * (size_t)H_];
    float xq1 = xp[1 * (size_t)H_];
    float xq2 = xp[2 * (size_t)H_];
    float xq3 = xp[3 * (size_t)H_];

#define P1_STEP(XV)                                                            \
    {                                                                          \
        const f32x2 X = (f32x2){(XV), (XV)};                                   \
        _Pragma("unroll")                                                      \
        for (int g = 0; g < 4; ++g) {                                          \
            f32x2 t   = __builtin_elementwise_fma(WIN[g], SI[g], X);           \
            f32x2 nSR = __builtin_elementwise_fma(WR[g], SR[g], t);            \
            f32x2 u   = WI[g] * SR[g];                                         \
            f32x2 nSI = __builtin_elementwise_fma(WR[g], SI[g], u);            \
            SR[g] = nSR; SI[g] = nSI;                                          \
        }                                                                      \
    }

#pragma unroll 4
    for (int l = 0; l < LCH - 4; ++l) {
        const float xf = xp[(size_t)(l + 4) * H_];
        P1_STEP(xq0);
        xq0 = xq1; xq1 = xq2; xq2 = xq3; xq3 = xf;
    }
#pragma unroll
    for (int l = LCH - 4; l < LCH; ++l) {
        P1_STEP(xq0);
        xq0 = xq1; xq1 = xq2; xq2 = xq3;
    }
#undef P1_STEP

    float2* Mp = M + (((size_t)b * CCH + c) * H_ + h) * NH + nb;
#pragma unroll
    for (int g = 0; g < 4; ++g) {
        float4 v; v.x = SR[g][0]; v.y = SI[g][0]; v.z = SR[g][1]; v.w = SI[g][1];
        *(float4*)&Mp[g * 2] = v;
    }
}

// ---------------- scan pass2: combine chunk carries IN-PLACE over M ----------------
__global__ __launch_bounds__(256)
void scan_pass2(const float* __restrict__ log_dt, const float* __restrict__ log_A_real,
                const float* __restrict__ A_imag, float2* __restrict__ M)
{
    const int idx = blockIdx.x * 256 + threadIdx.x;    // 262144 total
    const int n = idx & 31, h = (idx >> 5) & 511, b = idx >> 14;
    const float dt = expf(log_dt[h]);
    const float Ar = -expf(log_A_real[h * NH + n]);
    const float Ai = A_imag[h * NH + n];
    const float er = expf(Ar * dt);
    float wr = er * cosf(Ai * dt), wi = er * sinf(Ai * dt);
    // w^512 via 9 squarings (avoids large-argument trig)
#pragma unroll
    for (int s = 0; s < 9; ++s) {
        float nr = wr * wr - wi * wi;
        float ni = 2.0f * wr * wi;
        wr = nr; wi = ni;
    }
    float sre = 0.f, sim = 0.f;
#pragma unroll
    for (int c = 0; c < CCH; ++c) {
        const size_t mi_ = (((size_t)b * CCH + c) * H_ + h) * NH + n;
        float2 m = M[mi_];
        M[mi_] = make_float2(sre, sim);
        float nr = fmaf(wr, sre, fmaf(-wi, sim, m.x));
        float ni = fmaf(wr, sim, fmaf(wi, sre, m.y));
        sre = nr; sim = ni;
    }
}

// ---------------- scan pass3: seeded scan + y + D*x + gelu -> gT bf16 ----------------
// Same SoA decomposition as pass1; y accumulated packed (1 pk_fma/state),
// reduced with shfl_xor(16)+shfl_xor(32); no LDS.
__global__ __launch_bounds__(256)
void scan_pass3(const float* __restrict__ inp, const float* __restrict__ C,
                const float* __restrict__ log_dt, const float* __restrict__ log_A_real,
                const float* __restrict__ A_imag, const float* __restrict__ Dv,
                const float2* __restrict__ Sin, __hip_bfloat16* __restrict__ gT)
{
    const int b = blockIdx.x, hg = blockIdx.y, cq = blockIdx.z;
    const int tid = threadIdx.x;
    const int wv = tid >> 6, lane = tid & 63;
    const int c = cq * 4 + wv;
    const int hl = lane & 15, nb = (lane >> 4) * 8;
    const int h = hg * 16 + hl;

    f32x2 WR[4], WI[4], WIN[4], CR[4], CNI[4], SR[4], SI[4];
    const float dt = expf(log_dt[h]);
    const float2* Sp = Sin + (((size_t)b * CCH + c) * H_ + h) * NH + nb;
#pragma unroll
    for (int g = 0; g < 4; ++g) {
#pragma unroll
        for (int e = 0; e < 2; ++e) {
            const int n = nb + g * 2 + e;
            const float Ar = -expf(log_A_real[h * NH + n]);
            const float Ai = A_imag[h * NH + n];
            const float er = expf(Ar * dt);
            const float wrr = er * cosf(Ai * dt);
            const float wii = er * sinf(Ai * dt);
            const float m2 = Ar * Ar + Ai * Ai;
            const float nr = wrr - 1.0f, nim = wii;
            const float qr = (nr * Ar + nim * Ai) / m2;
            const float qi = (nim * Ar - nr * Ai) / m2;
            const float Crv = C[(h * NH + n) * 2 + 0];
            const float Civ = C[(h * NH + n) * 2 + 1];
            WR[g][e] = wrr;  WI[g][e] = wii;  WIN[g][e] = -wii;
            CR[g][e]  =  2.0f * (Crv * qr - Civ * qi);   // y += cr*Sr + cni*Si
            CNI[g][e] = -2.0f * (Crv * qi + Civ * qr);
            float2 sv = Sp[g * 2 + e];
            SR[g][e] = sv.x; SI[g][e] = sv.y;
        }
    }
    const float Dh = Dv[h];

    const float* xp = inp + ((size_t)b * L_ + (size_t)c * LCH) * H_ + h;
    __hip_bfloat16* gp = gT + ((size_t)b * L_ + (size_t)c * LCH) * H_ + h;

    float xq0 = xp[0 * (size_t)H_];
    float xq1 = xp[1 * (size_t)H_];
    float xq2 = xp[2 * (size_t)H_];
    float xq3 = xp[3 * (size_t)H_];

#define P3_STEP(LV, XV)                                                        \
    {                                                                          \
        const f32x2 X = (f32x2){(XV), (XV)};                                   \
        f32x2 yp = (f32x2){0.f, 0.f};                                          \
        _Pragma("unroll")                                                      \
        for (int g = 0; g < 4; ++g) {                                          \
            f32x2 t   = __builtin_elementwise_fma(WIN[g], SI[g], X);           \
            f32x2 nSR = __builtin_elementwise_fma(WR[g], SR[g], t);            \
            f32x2 u   = WI[g] * SR[g];                                         \
            f32x2 nSI = __builtin_elementwise_fma(WR[g], SI[g], u);            \
            SR[g] = nSR; SI[g] = nSI;                                          \
            yp = __builtin_elementwise_fma(CR[g], nSR, yp);                    \
            yp = __builtin_elementwise_fma(CNI[g], nSI, yp);                   \
        }                                                                      \
        float y = yp[0] + yp[1];                                               \
        y += __shfl_xor(y, 16);                                                \
        y += __shfl_xor(y, 32);                                                \
        const float v = fmaf(Dh, (XV), y);                                     \
        float u2 = v * fmaf(0.0356774081f, v * v, 0.797884561f);               \
        u2 = fmaxf(u2, -15.0f);                                                \
        const float e2 = __expf(-2.0f * u2);                                   \
        const float th = 1.0f - 2.0f * e2 * __builtin_amdgcn_rcpf(1.0f + e2);  \
        const float ge = 0.5f * v * (1.0f + th);                               \
        if (lane < 16) gp[(size_t)(LV) * H_] = __float2bfloat16(ge);           \
    }

#pragma unroll 2
    for (int l = 0; l < LCH - 4; ++l) {
        const float xf = xp[(size_t)(l + 4) * H_];
        P3_STEP(l, xq0);
        xq0 = xq1; xq1 = xq2; xq2 = xq3; xq3 = xf;
    }
#pragma unroll
    for (int l = LCH - 4; l < LCH; ++l) {
        P3_STEP(l, xq0);
        xq0 = xq1; xq1 = xq2; xq2 = xq3;
    }
#undef P3_STEP
}

__device__ __forceinline__ unsigned short bf16bits(float f) {
    __hip_bfloat16 hv = __float2bfloat16(f);
    return *reinterpret_cast<unsigned short*>(&hv);
}

// ---------------- GEMM1 + gate ----------------
__global__ __launch_bounds__(512)
void gemm1_kernel(const __hip_bfloat16* __restrict__ gT, const __hip_bfloat16* __restrict__ Wsel,
                  const float* __restrict__ bsel, __hip_bfloat16* __restrict__ gated)
{
    const int b  = blockIdx.y;
    const int l0 = blockIdx.x * 128;
    const int tid = threadIdx.x;
    const int wid = tid >> 6, lane = tid & 63;
    const int wrr = wid >> 2;      // 0..1
    const int wcc = wid & 3;       // 0..3
    const int lr  = lane & 15;
    const int lk8 = (lane >> 4) * 8;

    __shared__ short As[128][40];
    __shared__ short Bs[256][40];

    f32x4 acc[4][4];
#pragma unroll
    for (int i = 0; i < 4; ++i)
#pragma unroll
        for (int j = 0; j < 4; ++j) acc[i][j] = (f32x4){0.f, 0.f, 0.f, 0.f};

    const short* gsrc = (const short*)gT + ((size_t)b * L_ + l0) * H_;
    const short* wsrc = (const short*)Wsel;
    const int arow = tid >> 2, aseg = tid & 3;

    for (int ks = 0; ks < 16; ++ks) {
        const int k0 = ks * 32;
        uint4 av  = *(const uint4*)(gsrc + (size_t)arow * H_ + k0 + aseg * 8);
        uint4 bv0 = *(const uint4*)(wsrc + (size_t)arow * 512 + k0 + aseg * 8);
        uint4 bv1 = *(const uint4*)(wsrc + (size_t)(arow + 128) * 512 + k0 + aseg * 8);
        *(uint4*)&As[arow][aseg * 8]       = av;
        *(uint4*)&Bs[arow][aseg * 8]       = bv0;
        *(uint4*)&Bs[arow + 128][aseg * 8] = bv1;
        __syncthreads();

        bf16x8 af[4], bfr[4];
#pragma unroll
        for (int mi = 0; mi < 4; ++mi)
            af[mi] = *(const bf16x8*)&As[wrr * 64 + mi * 16 + lr][lk8];
#pragma unroll
        for (int ni = 0; ni < 4; ++ni) {
            int col = (ni < 2) ? (wcc * 32 + ni * 16) : (128 + wcc * 32 + (ni - 2) * 16);
            bfr[ni] = *(const bf16x8*)&Bs[col + lr][lk8];
        }
#pragma unroll
        for (int mi = 0; mi < 4; ++mi)
#pragma unroll
            for (int ni = 0; ni < 4; ++ni)
                acc[mi][ni] = __builtin_amdgcn_mfma_f32_16x16x32_bf16(af[mi], bfr[ni], acc[mi][ni], 0, 0, 0);
        __syncthreads();
    }

    const int lj4 = (lane >> 4) * 4;
#pragma unroll
    for (int mi = 0; mi < 4; ++mi) {
#pragma unroll
        for (int ni = 0; ni < 2; ++ni) {
            const int oa = wcc * 32 + ni * 16 + lr;
            const float ba  = bsel[oa];
            const float bbv = bsel[oa + 128];
            ushort4 pack;
            unsigned short* pu = (unsigned short*)&pack;
#pragma unroll
            for (int j = 0; j < 4; ++j) {
                float za = acc[mi][ni][j] + ba;
                float zb = acc[mi][ni + 2][j] + bbv;
                float gv = za * (1.0f / (1.0f + expf(-zb)));
                pu[j] = bf16bits(gv);
            }
            const int lrow = l0 + wrr * 64 + mi * 16 + lj4;
            *(ushort4*)((unsigned short*)gated + ((size_t)b * NPRED_ + oa) * L_ + lrow) = pack;
        }
    }
}

// ---------------- GEMM2: 64x64 tiles, BK=64, grid 128 blocks ----------------
__global__ __launch_bounds__(256)
void gemm2_kernel(const __hip_bfloat16* __restrict__ gated, const __hip_bfloat16* __restrict__ outw,
                  const float* __restrict__ outb, float* __restrict__ outp)
{
    const int b  = blockIdx.y;
    const int ot = blockIdx.x & 3, ht = blockIdx.x >> 2;
    const int o0 = ot * 64, hh0 = ht * 64;
    const int tid = threadIdx.x;
    const int wid = tid >> 6, lane = tid & 63;
    const int wrr = wid >> 1;      // 0..1
    const int wcc = wid & 1;       // 0..1
    const int lr  = lane & 15;
    const int lk8 = (lane >> 4) * 8;

    __shared__ short As[64][72];   // [hh][k] BK=64, +8 pad
    __shared__ short Bs[64][72];   // [o][k]

    f32x4 acc[2][2];
#pragma unroll
    for (int i = 0; i < 2; ++i)
#pragma unroll
        for (int j = 0; j < 2; ++j) acc[i][j] = (f32x4){0.f, 0.f, 0.f, 0.f};

    const short* asrc = (const short*)gated + ((size_t)b * NPRED_ + hh0) * L_;
    const short* bsrc = (const short*)outw + (size_t)o0 * L_;
    const int row = tid >> 2, seg = tid & 3;

    for (int ks = 0; ks < 64; ++ks) {
        const int k0 = ks * 64;
        uint4 a0 = *(const uint4*)(asrc + (size_t)row * L_ + k0 + seg * 8);
        uint4 a1 = *(const uint4*)(asrc + (size_t)row * L_ + k0 + 32 + seg * 8);
        uint4 b0 = *(const uint4*)(bsrc + (size_t)row * L_ + k0 + seg * 8);
        uint4 b1 = *(const uint4*)(bsrc + (size_t)row * L_ + k0 + 32 + seg * 8);
        __syncthreads();
        *(uint4*)&As[row][seg * 8]      = a0;
        *(uint4*)&As[row][32 + seg * 8] = a1;
        *(uint4*)&Bs[row][seg * 8]      = b0;
        *(uint4*)&Bs[row][32 + seg * 8] = b1;
        __syncthreads();

#pragma unroll
        for (int kk = 0; kk < 2; ++kk) {
            bf16x8 af[2], bfv[2];
#pragma unroll
            for (int mi = 0; mi < 2; ++mi)
                af[mi] = *(const bf16x8*)&As[wrr * 32 + mi * 16 + lr][kk * 32 + lk8];
#pragma unroll
            for (int ni = 0; ni < 2; ++ni)
                bfv[ni] = *(const bf16x8*)&Bs[wcc * 32 + ni * 16 + lr][kk * 32 + lk8];
#pragma unroll
            for (int mi = 0; mi < 2; ++mi)
#pragma unroll
                for (int ni = 0; ni < 2; ++ni)
                    acc[mi][ni] = __builtin_amdgcn_mfma_f32_16x16x32_bf16(af[mi], bfv[ni], acc[mi][ni], 0, 0, 0);
        }
    }

    const int lj4 = (lane >> 4) * 4;
#pragma unroll
    for (int mi = 0; mi < 2; ++mi) {
#pragma unroll
        for (int ni = 0; ni < 2; ++ni) {
            const int og = o0 + wcc * 32 + ni * 16 + lr;
            const float bo = outb[og];
            float4 v;
            v.x = acc[mi][ni][0] + bo;
            v.y = acc[mi][ni][1] + bo;
            v.z = acc[mi][ni][2] + bo;
            v.w = acc[mi][ni][3] + bo;
            const int hh = hh0 + wrr * 32 + mi * 16 + lj4;
            *(float4*)(outp + ((size_t)b * OUT_ + og) * NPRED_ + hh) = v;
        }
    }
}

// ---------------- launch ----------------
extern "C" void kernel_launch(void* const* d_in, const int* in_sizes, int n_in,
                              void* d_out, int out_size, void* d_ws, size_t ws_size,
                              hipStream_t stream)
{
    const float* inp        = (const float*)d_in[0];
    const float* C          = (const float*)d_in[2];
    const float* log_dt     = (const float*)d_in[3];
    const float* log_A_real = (const float*)d_in[4];
    const float* A_imag     = (const float*)d_in[5];
    const float* Dv         = (const float*)d_in[6];
    const float* conv_w     = (const float*)d_in[7];
    const float* conv_b     = (const float*)d_in[8];
    const float* out_w      = (const float*)d_in[9];
    const float* out_b      = (const float*)d_in[10];
    float* outp = (float*)d_out;

    // workspace layout (bytes). M (16 MiB exactly) aliases gated: M is dead
    // before gemm1 writes gated, and M is DISJOINT from gT (pass3 reads M
    // while writing gT). need == 86246400 (proven available).
    const size_t off_Wsel  = 0;                         // 262144
    const size_t off_outw  = 262144;                    // 2097152
    const size_t off_bsel  = 2359296;                   // 1024
    const size_t off_gT    = 2360320;                   // 67108864
    const size_t off_gated = 69469184;                  // 16777216
    const size_t off_M     = off_gated;                 // 16*8*512*32*8 = 16777216
    const size_t need      = 86246400;
    if (ws_size < need) return;

    char* ws = (char*)d_ws;
    __hip_bfloat16* Wsel  = (__hip_bfloat16*)(ws + off_Wsel);
    __hip_bfloat16* outw  = (__hip_bfloat16*)(ws + off_outw);
    float*          bselp = (float*)(ws + off_bsel);
    __hip_bfloat16* gT    = (__hip_bfloat16*)(ws + off_gT);
    __hip_bfloat16* gated = (__hip_bfloat16*)(ws + off_gated);
    float2*         M     = (float2*)(ws + off_M);

    const int prep_total = 256 * 512 + 256 * 4096 + 256;
    prep_kernel<<<(prep_total + 255) / 256, 256, 0, stream>>>(conv_w, conv_b, out_w, Wsel, bselp, outw);
    scan_pass1<<<dim3(16, 32, 2), 256, 0, stream>>>(inp, log_dt, log_A_real, A_imag, M);
    scan_pass2<<<1024, 256, 0, stream>>>(log_dt, log_A_real, A_imag, M);
    scan_pass3<<<dim3(16, 32, 2), 256, 0, stream>>>(inp, C, log_dt, log_A_real, A_imag, Dv, M, gT);
    gemm1_kernel<<<dim3(32, 16), 512, 0, stream>>>(gT, Wsel, bselp, gated);
    gemm2_kernel<<<dim3(8, 16), 256, 0, stream>>>(gated, outw, out_b, outp);
}

// Round 9
// 545.612 us; speedup vs baseline: 1.4813x; 1.0635x over previous
//
#include <hip/hip_runtime.h>
#include <hip/hip_bf16.h>
#include <math.h>

#define B_     16
#define L_     4096
#define H_     512
#define NH     32
#define OUT_   256
#define NPRED_ 128
#define CCH    8      // chunks along L
#define LCH    512    // chunk length

typedef __attribute__((ext_vector_type(8))) short bf16x8;
typedef __attribute__((ext_vector_type(4))) float f32x4;
typedef __attribute__((ext_vector_type(2))) float f32x2;

// modifier-free packed f32 ops (SoA layout needs no op_sel/neg) — non-volatile,
// register-only: the scheduler can reorder them freely.
#define PKFMA(D, A, Bv, Cv) asm("v_pk_fma_f32 %0, %1, %2, %3" : "=v"(D) : "v"(A), "v"(Bv), "v"(Cv))
#define PKFMA_ACC(D, A, Bv) asm("v_pk_fma_f32 %0, %1, %2, %0" : "+v"(D) : "v"(A), "v"(Bv))
#define PKMUL(D, A, Bv)     asm("v_pk_mul_f32 %0, %1, %2" : "=v"(D) : "v"(A), "v"(Bv))

// ---------------- prep: select + bf16-convert weights ----------------
__global__ void prep_kernel(const float* __restrict__ conv_w, const float* __restrict__ conv_b,
                            const float* __restrict__ out_w,
                            __hip_bfloat16* __restrict__ Wsel, float* __restrict__ bselp,
                            __hip_bfloat16* __restrict__ outw)
{
    int idx = blockIdx.x * blockDim.x + threadIdx.x;
    if (idx < 256 * 512) {
        int r = idx >> 9, hcol = idx & 511;
        int src = (r < 128) ? (384 + r) : (768 + r);   // 896 + (r-128)
        Wsel[idx] = __float2bfloat16(conv_w[src * H_ + hcol]);
    } else if (idx < 256 * 512 + 256 * 4096) {
        int i2 = idx - 256 * 512;
        outw[i2] = __float2bfloat16(out_w[i2]);
    } else if (idx < 256 * 512 + 256 * 4096 + 256) {
        int r = idx - 256 * 512 - 256 * 4096;
        int src = (r < 128) ? (384 + r) : (768 + r);
        bselp[r] = conv_b[src];
    }
}

// ---------------- scan pass1: per-chunk end-state ----------------
// 4 lanes/h x 16 h/wave, 8 states/lane (4 SoA pairs). grid (16 b, 32 hg, 2 cq),
// 4 waves/block, wave wv -> chunk cq*4+wv. 4096 waves = 4/SIMD. No LDS/barriers.
__global__ __launch_bounds__(256)
void scan_pass1(const float* __restrict__ inp, const float* __restrict__ log_dt,
                const float* __restrict__ log_A_real, const float* __restrict__ A_imag,
                float2* __restrict__ M)
{
    const int b = blockIdx.x, hg = blockIdx.y, cq = blockIdx.z;
    const int tid = threadIdx.x;
    const int wv = tid >> 6, lane = tid & 63;
    const int c = cq * 4 + wv;
    const int hl = lane & 15, nb = (lane >> 4) * 8;   // part*8
    const int h = hg * 16 + hl;

    f32x2 WR[4], WI[4], WIN[4], SR[4], SI[4];
    const float dt = expf(log_dt[h]);
#pragma unroll
    for (int g = 0; g < 4; ++g) {
#pragma unroll
        for (int e = 0; e < 2; ++e) {
            const int n = nb + g * 2 + e;
            const float Ar = -expf(log_A_real[h * NH + n]);
            const float Ai = A_imag[h * NH + n];
            const float er = expf(Ar * dt);
            WR[g][e] = er * cosf(Ai * dt);
            WI[g][e] = er * sinf(Ai * dt);
            WIN[g][e] = -WI[g][e];
        }
        SR[g] = (f32x2){0.f, 0.f};
        SI[g] = (f32x2){0.f, 0.f};
    }

    const float* xp = inp + ((size_t)b * L_ + (size_t)c * LCH) * H_ + h;

    float xc[8], xn[8];
#pragma unroll
    for (int i = 0; i < 8; ++i) xc[i] = xp[(size_t)i * H_];

#define P1_STEP(XV)                                                            \
    {                                                                          \
        f32x2 X; X[0] = (XV); X[1] = (XV);                                     \
        _Pragma("unroll")                                                      \
        for (int g = 0; g < 4; ++g) {                                          \
            f32x2 t1, t2, nSR, nSI;                                            \
            PKFMA(t1, WIN[g], SI[g], X);                                       \
            PKFMA(nSR, WR[g], SR[g], t1);                                      \
            PKMUL(t2, WI[g], SR[g]);                                           \
            PKFMA(nSI, WR[g], SI[g], t2);                                      \
            SR[g] = nSR; SI[g] = nSI;                                          \
        }                                                                      \
    }

    for (int blk = 0; blk < 64; ++blk) {
        if (blk < 63) {
#pragma unroll
            for (int i = 0; i < 8; ++i) xn[i] = xp[(size_t)(blk * 8 + 8 + i) * H_];
        }
#pragma unroll
        for (int s = 0; s < 8; ++s) P1_STEP(xc[s]);
#pragma unroll
        for (int i = 0; i < 8; ++i) xc[i] = xn[i];
    }
#undef P1_STEP

    float2* Mp = M + (((size_t)b * CCH + c) * H_ + h) * NH + nb;
#pragma unroll
    for (int g = 0; g < 4; ++g) {
        float4 v; v.x = SR[g][0]; v.y = SI[g][0]; v.z = SR[g][1]; v.w = SI[g][1];
        *(float4*)&Mp[g * 2] = v;
    }
}

// ---------------- scan pass2: combine chunk carries IN-PLACE over M ----------------
__global__ __launch_bounds__(256)
void scan_pass2(const float* __restrict__ log_dt, const float* __restrict__ log_A_real,
                const float* __restrict__ A_imag, float2* __restrict__ M)
{
    const int idx = blockIdx.x * 256 + threadIdx.x;    // 262144 total
    const int n = idx & 31, h = (idx >> 5) & 511, b = idx >> 14;
    const float dt = expf(log_dt[h]);
    const float Ar = -expf(log_A_real[h * NH + n]);
    const float Ai = A_imag[h * NH + n];
    const float er = expf(Ar * dt);
    float wr = er * cosf(Ai * dt), wi = er * sinf(Ai * dt);
    // w^512 via 9 squarings (avoids large-argument trig)
#pragma unroll
    for (int s = 0; s < 9; ++s) {
        float nr = wr * wr - wi * wi;
        float ni = 2.0f * wr * wi;
        wr = nr; wi = ni;
    }
    float sre = 0.f, sim = 0.f;
#pragma unroll
    for (int c = 0; c < CCH; ++c) {
        const size_t mi_ = (((size_t)b * CCH + c) * H_ + h) * NH + n;
        float2 m = M[mi_];
        M[mi_] = make_float2(sre, sim);
        float nr = fmaf(wr, sre, fmaf(-wi, sim, m.x));
        float ni = fmaf(wr, sim, fmaf(wi, sre, m.y));
        sre = nr; sim = ni;
    }
}

// ---------------- scan pass3: seeded scan + y + D*x + gelu -> gT bf16 ----------------
// Per step: state update + packed y-accum + 1 fold-add ONLY. Every 8 steps:
// batched 16-swizzle reduce, then each of the 4 lane-parts gelu+stores 2 rows
// (cndmask 1-of-4 selection, all-lane stores, no exec churn).
__global__ __launch_bounds__(256)
void scan_pass3(const float* __restrict__ inp, const float* __restrict__ C,
                const float* __restrict__ log_dt, const float* __restrict__ log_A_real,
                const float* __restrict__ A_imag, const float* __restrict__ Dv,
                const float2* __restrict__ Sin, __hip_bfloat16* __restrict__ gT)
{
    const int b = blockIdx.x, hg = blockIdx.y, cq = blockIdx.z;
    const int tid = threadIdx.x;
    const int wv = tid >> 6, lane = tid & 63;
    const int c = cq * 4 + wv;
    const int hl = lane & 15, nb = (lane >> 4) * 8;
    const int h = hg * 16 + hl;
    const bool pb0 = ((lane >> 4) & 1) != 0;
    const bool pb1 = ((lane >> 4) & 2) != 0;
    const int p = lane >> 4;

    f32x2 WR[4], WI[4], WIN[4], CR[4], CNI[4], SR[4], SI[4];
    const float dt = expf(log_dt[h]);
    const float2* Sp = Sin + (((size_t)b * CCH + c) * H_ + h) * NH + nb;
#pragma unroll
    for (int g = 0; g < 4; ++g) {
#pragma unroll
        for (int e = 0; e < 2; ++e) {
            const int n = nb + g * 2 + e;
            const float Ar = -expf(log_A_real[h * NH + n]);
            const float Ai = A_imag[h * NH + n];
            const float er = expf(Ar * dt);
            const float wrr = er * cosf(Ai * dt);
            const float wii = er * sinf(Ai * dt);
            const float m2 = Ar * Ar + Ai * Ai;
            const float nr = wrr - 1.0f, nim = wii;
            const float qr = (nr * Ar + nim * Ai) / m2;
            const float qi = (nim * Ar - nr * Ai) / m2;
            const float Crv = C[(h * NH + n) * 2 + 0];
            const float Civ = C[(h * NH + n) * 2 + 1];
            WR[g][e] = wrr;  WI[g][e] = wii;  WIN[g][e] = -wii;
            CR[g][e]  =  2.0f * (Crv * qr - Civ * qi);   // y += cr*Sr + cni*Si
            CNI[g][e] = -2.0f * (Crv * qi + Civ * qr);
            float2 sv = Sp[g * 2 + e];
            SR[g][e] = sv.x; SI[g][e] = sv.y;
        }
    }
    const float Dh = Dv[h];

    const float* xp = inp + ((size_t)b * L_ + (size_t)c * LCH) * H_ + h;
    __hip_bfloat16* gp = gT + ((size_t)b * L_ + (size_t)c * LCH) * H_ + h;

    float xc[8], xn[8];
#pragma unroll
    for (int i = 0; i < 8; ++i) xc[i] = xp[(size_t)i * H_];

    for (int blk = 0; blk < 64; ++blk) {
        if (blk < 63) {
#pragma unroll
            for (int i = 0; i < 8; ++i) xn[i] = xp[(size_t)(blk * 8 + 8 + i) * H_];
        }
        float y8[8];
#pragma unroll
        for (int s = 0; s < 8; ++s) {
            f32x2 X; X[0] = xc[s]; X[1] = xc[s];
            f32x2 yp;
#pragma unroll
            for (int g = 0; g < 4; ++g) {
                f32x2 t1, t2, nSR, nSI;
                PKFMA(t1, WIN[g], SI[g], X);
                PKFMA(nSR, WR[g], SR[g], t1);
                PKMUL(t2, WI[g], SR[g]);
                PKFMA(nSI, WR[g], SI[g], t2);
                SR[g] = nSR; SI[g] = nSI;
                if (g == 0) {
                    PKMUL(yp, CR[0], nSR);
                } else {
                    PKFMA_ACC(yp, CR[g], nSR);
                }
                PKFMA_ACC(yp, CNI[g], nSI);
            }
            y8[s] = yp[0] + yp[1];
        }
        // batched cross-part reduce (parts live at lane ^16, ^32)
#pragma unroll
        for (int s = 0; s < 8; ++s) y8[s] += __shfl_xor(y8[s], 16);
#pragma unroll
        for (int s = 0; s < 8; ++s) y8[s] += __shfl_xor(y8[s], 32);
        // part p finalizes rows 2p and 2p+1 (compile-time-safe 1-of-4 selects)
#pragma unroll
        for (int e = 0; e < 2; ++e) {
            const float ys = e == 0
                ? (pb1 ? (pb0 ? y8[6] : y8[4]) : (pb0 ? y8[2] : y8[0]))
                : (pb1 ? (pb0 ? y8[7] : y8[5]) : (pb0 ? y8[3] : y8[1]));
            const float xs = e == 0
                ? (pb1 ? (pb0 ? xc[6] : xc[4]) : (pb0 ? xc[2] : xc[0]))
                : (pb1 ? (pb0 ? xc[7] : xc[5]) : (pb0 ? xc[3] : xc[1]));
            const float v = fmaf(Dh, xs, ys);
            float u2 = v * fmaf(0.0356774081f, v * v, 0.797884561f);
            u2 = fmaxf(u2, -15.0f);
            const float e2 = __expf(-2.0f * u2);
            const float th = 1.0f - 2.0f * e2 * __builtin_amdgcn_rcpf(1.0f + e2);
            const float ge = 0.5f * v * (1.0f + th);
            gp[(size_t)(blk * 8 + p * 2 + e) * H_] = __float2bfloat16(ge);
        }
#pragma unroll
        for (int i = 0; i < 8; ++i) xc[i] = xn[i];
    }
}

__device__ __forceinline__ unsigned short bf16bits(float f) {
    __hip_bfloat16 hv = __float2bfloat16(f);
    return *reinterpret_cast<unsigned short*>(&hv);
}

// ---------------- GEMM1 + gate ----------------
__global__ __launch_bounds__(512)
void gemm1_kernel(const __hip_bfloat16* __restrict__ gT, const __hip_bfloat16* __restrict__ Wsel,
                  const float* __restrict__ bsel, __hip_bfloat16* __restrict__ gated)
{
    const int b  = blockIdx.y;
    const int l0 = blockIdx.x * 128;
    const int tid = threadIdx.x;
    const int wid = tid >> 6, lane = tid & 63;
    const int wrr = wid >> 2;      // 0..1
    const int wcc = wid & 3;       // 0..3
    const int lr  = lane & 15;
    const int lk8 = (lane >> 4) * 8;

    __shared__ short As[128][40];
    __shared__ short Bs[256][40];

    f32x4 acc[4][4];
#pragma unroll
    for (int i = 0; i < 4; ++i)
#pragma unroll
        for (int j = 0; j < 4; ++j) acc[i][j] = (f32x4){0.f, 0.f, 0.f, 0.f};

    const short* gsrc = (const short*)gT + ((size_t)b * L_ + l0) * H_;
    const short* wsrc = (const short*)Wsel;
    const int arow = tid >> 2, aseg = tid & 3;

    for (int ks = 0; ks < 16; ++ks) {
        const int k0 = ks * 32;
        uint4 av  = *(const uint4*)(gsrc + (size_t)arow * H_ + k0 + aseg * 8);
        uint4 bv0 = *(const uint4*)(wsrc + (size_t)arow * 512 + k0 + aseg * 8);
        uint4 bv1 = *(const uint4*)(wsrc + (size_t)(arow + 128) * 512 + k0 + aseg * 8);
        *(uint4*)&As[arow][aseg * 8]       = av;
        *(uint4*)&Bs[arow][aseg * 8]       = bv0;
        *(uint4*)&Bs[arow + 128][aseg * 8] = bv1;
        __syncthreads();

        bf16x8 af[4], bfr[4];
#pragma unroll
        for (int mi = 0; mi < 4; ++mi)
            af[mi] = *(const bf16x8*)&As[wrr * 64 + mi * 16 + lr][lk8];
#pragma unroll
        for (int ni = 0; ni < 4; ++ni) {
            int col = (ni < 2) ? (wcc * 32 + ni * 16) : (128 + wcc * 32 + (ni - 2) * 16);
            bfr[ni] = *(const bf16x8*)&Bs[col + lr][lk8];
        }
#pragma unroll
        for (int mi = 0; mi < 4; ++mi)
#pragma unroll
            for (int ni = 0; ni < 4; ++ni)
                acc[mi][ni] = __builtin_amdgcn_mfma_f32_16x16x32_bf16(af[mi], bfr[ni], acc[mi][ni], 0, 0, 0);
        __syncthreads();
    }

    const int lj4 = (lane >> 4) * 4;
#pragma unroll
    for (int mi = 0; mi < 4; ++mi) {
#pragma unroll
        for (int ni = 0; ni < 2; ++ni) {
            const int oa = wcc * 32 + ni * 16 + lr;
            const float ba  = bsel[oa];
            const float bbv = bsel[oa + 128];
            ushort4 pack;
            unsigned short* pu = (unsigned short*)&pack;
#pragma unroll
            for (int j = 0; j < 4; ++j) {
                float za = acc[mi][ni][j] + ba;
                float zb = acc[mi][ni + 2][j] + bbv;
                float gv = za * (1.0f / (1.0f + expf(-zb)));
                pu[j] = bf16bits(gv);
            }
            const int lrow = l0 + wrr * 64 + mi * 16 + lj4;
            *(ushort4*)((unsigned short*)gated + ((size_t)b * NPRED_ + oa) * L_ + lrow) = pack;
        }
    }
}

// ---------------- GEMM2: 64x64 tiles, BK=64, grid 128 blocks ----------------
__global__ __launch_bounds__(256)
void gemm2_kernel(const __hip_bfloat16* __restrict__ gated, const __hip_bfloat16* __restrict__ outw,
                  const float* __restrict__ outb, float* __restrict__ outp)
{
    const int b  = blockIdx.y;
    const int ot = blockIdx.x & 3, ht = blockIdx.x >> 2;
    const int o0 = ot * 64, hh0 = ht * 64;
    const int tid = threadIdx.x;
    const int wid = tid >> 6, lane = tid & 63;
    const int wrr = wid >> 1;      // 0..1
    const int wcc = wid & 1;       // 0..1
    const int lr  = lane & 15;
    const int lk8 = (lane >> 4) * 8;

    __shared__ short As[64][72];   // [hh][k] BK=64, +8 pad
    __shared__ short Bs[64][72];   // [o][k]

    f32x4 acc[2][2];
#pragma unroll
    for (int i = 0; i < 2; ++i)
#pragma unroll
        for (int j = 0; j < 2; ++j) acc[i][j] = (f32x4){0.f, 0.f, 0.f, 0.f};

    const short* asrc = (const short*)gated + ((size_t)b * NPRED_ + hh0) * L_;
    const short* bsrc = (const short*)outw + (size_t)o0 * L_;
    const int row = tid >> 2, seg = tid & 3;

    for (int ks = 0; ks < 64; ++ks) {
        const int k0 = ks * 64;
        uint4 a0 = *(const uint4*)(asrc + (size_t)row * L_ + k0 + seg * 8);
        uint4 a1 = *(const uint4*)(asrc + (size_t)row * L_ + k0 + 32 + seg * 8);
        uint4 b0 = *(const uint4*)(bsrc + (size_t)row * L_ + k0 + seg * 8);
        uint4 b1 = *(const uint4*)(bsrc + (size_t)row * L_ + k0 + 32 + seg * 8);
        __syncthreads();
        *(uint4*)&As[row][seg * 8]      = a0;
        *(uint4*)&As[row][32 + seg * 8] = a1;
        *(uint4*)&Bs[row][seg * 8]      = b0;
        *(uint4*)&Bs[row][32 + seg * 8] = b1;
        __syncthreads();

#pragma unroll
        for (int kk = 0; kk < 2; ++kk) {
            bf16x8 af[2], bfv[2];
#pragma unroll
            for (int mi = 0; mi < 2; ++mi)
                af[mi] = *(const bf16x8*)&As[wrr * 32 + mi * 16 + lr][kk * 32 + lk8];
#pragma unroll
            for (int ni = 0; ni < 2; ++ni)
                bfv[ni] = *(const bf16x8*)&Bs[wcc * 32 + ni * 16 + lr][kk * 32 + lk8];
#pragma unroll
            for (int mi = 0; mi < 2; ++mi)
#pragma unroll
                for (int ni = 0; ni < 2; ++ni)
                    acc[mi][ni] = __builtin_amdgcn_mfma_f32_16x16x32_bf16(af[mi], bfv[ni], acc[mi][ni], 0, 0, 0);
        }
    }

    const int lj4 = (lane >> 4) * 4;
#pragma unroll
    for (int mi = 0; mi < 2; ++mi) {
#pragma unroll
        for (int ni = 0; ni < 2; ++ni) {
            const int og = o0 + wcc * 32 + ni * 16 + lr;
            const float bo = outb[og];
            float4 v;
            v.x = acc[mi][ni][0] + bo;
            v.y = acc[mi][ni][1] + bo;
            v.z = acc[mi][ni][2] + bo;
            v.w = acc[mi][ni][3] + bo;
            const int hh = hh0 + wrr * 32 + mi * 16 + lj4;
            *(float4*)(outp + ((size_t)b * OUT_ + og) * NPRED_ + hh) = v;
        }
    }
}

// ---------------- launch ----------------
extern "C" void kernel_launch(void* const* d_in, const int* in_sizes, int n_in,
                              void* d_out, int out_size, void* d_ws, size_t ws_size,
                              hipStream_t stream)
{
    const float* inp        = (const float*)d_in[0];
    const float* C          = (const float*)d_in[2];
    const float* log_dt     = (const float*)d_in[3];
    const float* log_A_real = (const float*)d_in[4];
    const float* A_imag     = (const float*)d_in[5];
    const float* Dv         = (const float*)d_in[6];
    const float* conv_w     = (const float*)d_in[7];
    const float* conv_b     = (const float*)d_in[8];
    const float* out_w      = (const float*)d_in[9];
    const float* out_b      = (const float*)d_in[10];
    float* outp = (float*)d_out;

    // workspace layout (bytes). M (16 MiB exactly) aliases gated: M is dead
    // before gemm1 writes gated, and M is DISJOINT from gT (pass3 reads M
    // while writing gT). need == 86246400 (proven available).
    const size_t off_Wsel  = 0;                         // 262144
    const size_t off_outw  = 262144;                    // 2097152
    const size_t off_bsel  = 2359296;                   // 1024
    const size_t off_gT    = 2360320;                   // 67108864
    const size_t off_gated = 69469184;                  // 16777216
    const size_t off_M     = off_gated;                 // 16*8*512*32*8 = 16777216
    const size_t need      = 86246400;
    if (ws_size < need) return;

    char* ws = (char*)d_ws;
    __hip_bfloat16* Wsel  = (__hip_bfloat16*)(ws + off_Wsel);
    __hip_bfloat16* outw  = (__hip_bfloat16*)(ws + off_outw);
    float*          bselp = (float*)(ws + off_bsel);
    __hip_bfloat16* gT    = (__hip_bfloat16*)(ws + off_gT);
    __hip_bfloat16* gated = (__hip_bfloat16*)(ws + off_gated);
    float2*         M     = (float2*)(ws + off_M);

    const int prep_total = 256 * 512 + 256 * 4096 + 256;
    prep_kernel<<<(prep_total + 255) / 256, 256, 0, stream>>>(conv_w, conv_b, out_w, Wsel, bselp, outw);
    scan_pass1<<<dim3(16, 32, 2), 256, 0, stream>>>(inp, log_dt, log_A_real, A_imag, M);
    scan_pass2<<<1024, 256, 0, stream>>>(log_dt, log_A_real, A_imag, M);
    scan_pass3<<<dim3(16, 32, 2), 256, 0, stream>>>(inp, C, log_dt, log_A_real, A_imag, Dv, M, gT);
    gemm1_kernel<<<dim3(32, 16), 512, 0, stream>>>(gT, Wsel, bselp, gated);
    gemm2_kernel<<<dim3(8, 16), 256, 0, stream>>>(gated, outw, out_b, outp);
}